// Round 3
// baseline (796.302 us; speedup 1.0000x reference)
//
#include <hip/hip_runtime.h>

// Problem constants (N=1)
constexpr int W_ = 160;   // input W (x), output dim 1
constexpr int H_ = 192;   // input H (y), output dim 2
constexpr int D_ = 64;    // input D (z), output dim 4 (innermost)
constexpr int C_ = 32;
constexpr int HW_  = H_ * W_;          // 30720
constexpr int DHWi = D_ * HW_;         // 1966080
constexpr int CD   = C_ * D_;          // 2048

// Output tile per block: (w:32, h:12, d:16, c:1).
// Grid = 32 c (slowest) x [4 dt x 16 hs x 5 wt] spatial = 10240 blocks.
// R1/R2 lesson: scattered gathers are pinned at ~1.8 TB/s by miss-latency x
// outstanding-miss cap (waves 12->24/CU: null; 4x load clustering: null).
// R3: convert ALL global reads to dense streams. Each block computes the exact
// input bounding box of its output tile (8 corner evals; fma is weakly
// monotone per argument -> corner bounds are rigorous), stages the box into
// LDS with dense batched row copies, then gathers trilinear taps from LDS.
// Box is theta-dependent: if the full-tile box exceeds LDS, split the tile
// into two w:16 halves (box shrinks ~45%); if still too big (absurd theta),
// run a correct global-gather fallback.
constexpr int TW = 32, TH = 12, TD = 16;
constexpr int NWT = W_ / TW;           // 5
constexpr int NHT = H_ / TH;           // 16
constexpr int NDT = D_ / TD;           // 4
constexpr int SPATIAL = NWT * NHT * NDT; // 320
constexpr int LDSF = 20480;            // 80 KB -> 2 blocks/CU (160 KB LDS/CU)

__global__ void __launch_bounds__(256, 2)
affine_grid_sample_kernel(const float* __restrict__ inp,
                          const float* __restrict__ th,
                          float* __restrict__ out)
{
    __shared__ float Lb[LDSF];

    const int t = threadIdx.x;

    int bid = blockIdx.x;
    const int c = bid / SPATIAL;       // c slowest: co-resident blocks share planes
    int sp = bid - c * SPATIAL;
    const int wt = sp % NWT; sp /= NWT;
    const int hs = sp % NHT;
    const int dt = sp / NHT;
    const int w0 = wt * TW, h0 = hs * TH, d0 = dt * TD;

    const float th0=th[0], th1=th[1], th2 =th[2],  th3 =th[3];
    const float th4=th[4], th5=th[5], th6 =th[6],  th7 =th[7];
    const float th8=th[8], th9=th[9], th10=th[10], th11=th[11];

    const float* __restrict__ pc = inp + (size_t)c * DHWi;

    auto XX = [&](int w){ return fmaf((float)w, 2.0f/(W_-1), -1.0f); };
    auto YY = [&](int h){ return fmaf((float)h, 2.0f/(H_-1), -1.0f); };
    auto ZZ = [&](int d){ return fmaf((float)d, 2.0f/(D_-1), -1.0f); };
    // EXACT same expression trees as the per-point eval below (required for
    // the rigorous-bounds argument).
    auto PX = [&](float xx, float yy, float zz){
        return (fmaf(th0, xx, fmaf(th1, yy, fmaf(th2, zz, th3))) + 1.0f) * (0.5f*(W_-1)); };
    auto PY = [&](float xx, float yy, float zz){
        return (fmaf(th4, xx, fmaf(th5, yy, fmaf(th6, zz, th7))) + 1.0f) * (0.5f*(H_-1)); };
    auto PZ = [&](float xx, float yy, float zz){
        return (fmaf(th8, xx, fmaf(th9, yy, fmaf(th10, zz, th11))) + 1.0f) * (0.5f*(D_-1)); };

    struct Box { int xlo, ylo, zlo, BX, BY, BZ; bool fits; };
    auto make_box = [&](int wa, int wspan) -> Box {
        float pxmn= 1e30f, pxmx=-1e30f, pymn= 1e30f, pymx=-1e30f,
              pzmn= 1e30f, pzmx=-1e30f;
        #pragma unroll
        for (int ci = 0; ci < 8; ++ci) {
            const int cw = (ci & 1) ? wa + wspan - 1 : wa;
            const int ch = (ci & 2) ? h0 + TH - 1    : h0;
            const int cd = (ci & 4) ? d0 + TD - 1    : d0;
            const float xx = XX(cw), yy = YY(ch), zz = ZZ(cd);
            const float px = PX(xx,yy,zz), py = PY(xx,yy,zz), pz = PZ(xx,yy,zz);
            pxmn = fminf(pxmn, px); pxmx = fmaxf(pxmx, px);
            pymn = fminf(pymn, py); pymx = fmaxf(pymx, py);
            pzmn = fminf(pzmn, pz); pzmx = fmaxf(pzmx, pz);
        }
        Box b;
        b.xlo = max((int)floorf(pxmn), 0);
        int xhi = min((int)floorf(pxmx) + 1, W_ - 1);
        b.ylo = max((int)floorf(pymn), 0);
        int yhi = min((int)floorf(pymx) + 1, H_ - 1);
        b.zlo = max((int)floorf(pzmn), 0);
        int zhi = min((int)floorf(pzmx) + 1, D_ - 1);
        b.BX = xhi - b.xlo + 1; if (b.BX < 1) { b.BX = 1; b.xlo = 0; }
        b.BY = yhi - b.ylo + 1; if (b.BY < 1) { b.BY = 1; b.ylo = 0; }
        b.BZ = zhi - b.zlo + 1; if (b.BZ < 1) { b.BZ = 1; b.zlo = 0; }
        const int R = b.BZ * b.BY;
        b.fits = (b.BX <= 64) && (b.BY <= 128) && (R <= 512) &&
                 (b.BX * R + 1 <= LDSF);
        return b;
    };

    Box full = make_box(w0, TW);
    const int nsplit = full.fits ? 1 : 2;

    const int dd = t & 15;       // d within tile (store lanes d-contiguous)
    const int ww = t >> 4;       // 0..15: w within 16-group

    for (int s = 0; s < nsplit; ++s) {
        const int wspan = TW / nsplit;
        const int wa = w0 + s * wspan;
        const Box b = (nsplit == 1) ? full : make_box(wa, wspan);
        const int xlo = b.xlo, ylo = b.ylo, zlo = b.zlo;
        const int BX = b.BX, BY = b.BY, BZ = b.BZ;
        const int R = BZ * BY;
        const bool fits = b.fits;

        if (fits) {
            // ---- stage: dense row copies, batched 8-deep for guaranteed MLP.
            // wave wv handles rows rb..rb+7, rb += 32. Row index r -> (bz,by)
            // via 18-bit magic (exact for R<=512, BY<=128: (BY-1)(512+BY)<2^18).
            const int wv = t >> 6, lane = t & 63;
            const unsigned m18 = (262144u + (unsigned)BY - 1) / (unsigned)BY;
            const float* __restrict__ gpz = pc + zlo * HW_ + ylo * W_ + xlo;
            const bool lx = (lane < BX);
            for (int rb = wv * 8; rb < R; rb += 32) {
                float v[8];
                #pragma unroll
                for (int j = 0; j < 8; ++j) {
                    const int r  = min(rb + j, R - 1);
                    const int bz = (int)(((unsigned)r * m18) >> 18);
                    const int by = r - bz * BY;
                    v[j] = lx ? gpz[bz * HW_ + by * W_ + lane] : 0.0f;
                }
                #pragma unroll
                for (int j = 0; j < 8; ++j) {
                    const int r = rb + j;
                    if (r < R && lx) Lb[r * BX + lane] = v[j];
                }
            }
        }
        __syncthreads();

        // ---- gather from LDS (or global fallback), direct NT stores ----
        const int wsteps = wspan >> 4;          // 2 if nsplit==1 else 1
        const int d = d0 + dd;
        const float kzx = fmaf(th2,  ZZ(d), th3);
        const float kzy = fmaf(th6,  ZZ(d), th7);
        const float kzz = fmaf(th10, ZZ(d), th11);
        for (int wi = 0; wi < wsteps; ++wi) {
            const int w = wa + wi * 16 + ww;
            const float xx = XX(w);
            float* ob = out + ((size_t)w * H_ + h0) * CD + (size_t)c * D_ + d;
            #pragma unroll 2
            for (int hh = 0; hh < TH; ++hh) {
                const float yy = YY(h0 + hh);
                const float px = (fmaf(th0, xx, fmaf(th1, yy, kzx)) + 1.0f) * (0.5f*(W_-1));
                const float py = (fmaf(th4, xx, fmaf(th5, yy, kzy)) + 1.0f) * (0.5f*(H_-1));
                const float pz = (fmaf(th8, xx, fmaf(th9, yy, kzz)) + 1.0f) * (0.5f*(D_-1));
                const float fx = floorf(px), fy = floorf(py), fz = floorf(pz);
                const int ix0 = (int)fx, iy0 = (int)fy, iz0 = (int)fz;
                const float wx = px - fx, wy = py - fy, wz = pz - fz;
                // zeros-padding: per-axis weights zeroed for OOB corners
                const float u0r = ((unsigned)ix0     < (unsigned)W_) ? 1.0f - wx : 0.0f;
                const float u1r = ((unsigned)(ix0+1) < (unsigned)W_) ? wx        : 0.0f;
                const float v0  = ((unsigned)iy0     < (unsigned)H_) ? 1.0f - wy : 0.0f;
                const float v1  = ((unsigned)(iy0+1) < (unsigned)H_) ? wy        : 0.0f;
                const float s0  = ((unsigned)iz0     < (unsigned)D_) ? 1.0f - wz : 0.0f;
                const float s1  = ((unsigned)(iz0+1) < (unsigned)D_) ? wz        : 0.0f;
                const int cx0 = min(max(ix0,   0), W_-1);
                const int cy0 = min(max(iy0,   0), H_-1);
                const int cy1 = min(max(iy0+1, 0), H_-1);
                const int cz0 = min(max(iz0,   0), D_-1);
                const int cz1 = min(max(iz0+1, 0), D_-1);
                float val;
                if (__builtin_expect(fits, 1)) {
                    // x-pair via one ds_read2: L[i], L[i+1]. Edge ix0=-1:
                    // shift-down swap (u0 takes u1's weight, reads box x=0).
                    float u0 = u0r, u1 = u1r;
                    if (ix0 < 0) { u0 = u1r; u1 = 0.0f; }
                    const int bx = cx0 - xlo;
                    const int r00 = (cz0 - zlo) * BY + (cy0 - ylo);
                    const int r01 = (cz0 - zlo) * BY + (cy1 - ylo);
                    const int r10 = (cz1 - zlo) * BY + (cy0 - ylo);
                    const int r11 = (cz1 - zlo) * BY + (cy1 - ylo);
                    // unsigned-min clamp: insurance for degenerate boxes only
                    const unsigned cap = (unsigned)(LDSF - 2);
                    const unsigned i00 = min((unsigned)(r00 * BX + bx), cap);
                    const unsigned i01 = min((unsigned)(r01 * BX + bx), cap);
                    const unsigned i10 = min((unsigned)(r10 * BX + bx), cap);
                    const unsigned i11 = min((unsigned)(r11 * BX + bx), cap);
                    const float a0 = u0 * Lb[i00] + u1 * Lb[i00 + 1];
                    const float a1 = u0 * Lb[i01] + u1 * Lb[i01 + 1];
                    const float a2 = u0 * Lb[i10] + u1 * Lb[i10 + 1];
                    const float a3 = u0 * Lb[i11] + u1 * Lb[i11 + 1];
                    const float e0 = v0 * a0 + v1 * a1;
                    const float e1 = v0 * a2 + v1 * a3;
                    val = s0 * e0 + s1 * e1;
                } else {
                    // global-gather fallback (plain weights, explicit cx1)
                    const int cx1 = min(max(ix0+1, 0), W_-1);
                    const int g00 = (cz0 * H_ + cy0) * W_;
                    const int g01 = (cz0 * H_ + cy1) * W_;
                    const int g10 = (cz1 * H_ + cy0) * W_;
                    const int g11 = (cz1 * H_ + cy1) * W_;
                    const float a0 = u0r * pc[g00+cx0] + u1r * pc[g00+cx1];
                    const float a1 = u0r * pc[g01+cx0] + u1r * pc[g01+cx1];
                    const float a2 = u0r * pc[g10+cx0] + u1r * pc[g10+cx1];
                    const float a3 = u0r * pc[g11+cx0] + u1r * pc[g11+cx1];
                    const float e0 = v0 * a0 + v1 * a1;
                    const float e1 = v0 * a2 + v1 * a3;
                    val = s0 * e0 + s1 * e1;
                }
                // output is write-once streaming: non-temporal
                __builtin_nontemporal_store(val, ob + (size_t)hh * CD);
            }
        }
        __syncthreads();
    }
}

extern "C" void kernel_launch(void* const* d_in, const int* in_sizes, int n_in,
                              void* d_out, int out_size, void* d_ws, size_t ws_size,
                              hipStream_t stream)
{
    const float* inp = (const float*)d_in[0];   // [1,32,64,192,160] fp32
    const float* th  = (const float*)d_in[1];   // 12 fp32
    float* out = (float*)d_out;                 // [1,160,192,32,64] fp32

    hipLaunchKernelGGL(affine_grid_sample_kernel, dim3(C_ * SPATIAL), dim3(256),
                       0, stream, inp, th, out);
}

// Round 4
// 709.080 us; speedup vs baseline: 1.1230x; 1.1230x over previous
//
#include <hip/hip_runtime.h>

// Problem constants (N=1)
constexpr int W_ = 160;   // input W (x), output dim 1
constexpr int H_ = 192;   // input H (y), output dim 2
constexpr int D_ = 64;    // input D (z), output dim 4 (innermost)
constexpr int C_ = 32;
constexpr int HW_  = H_ * W_;          // 30720
constexpr int DHWi = D_ * HW_;         // 1966080
constexpr int CD   = C_ * D_;          // 2048

// R1-R3 lesson: scattered 24w/CU, clustered 16w/CU, dense-staged 8w/CU ALL plateau
// at ~1.85 TB/s => per-CU outstanding-miss cap x miss LATENCY is the wall; neither
// wave count nor MLP nor density moves it. Co-resident working set was ~83 MB
// (c fastest!) -> L3 latency on every read. R4: L2 PHASE SCHEDULING.
//   grid = xcd(bid&7) x 16 phases x 80 spatial; phase=(c,dt), dt fastest.
//   One phase's input slab ~29 z-planes ~3.5 MB <= 4 MB per-XCD L2.
//   Residency throttled to 3 blocks/CU (52 KB dynamic LDS) so each XCD's window
//   ~1.2 phases stays L2-sized. Reads become L2 hits -> latency /4 -> BW x4 at
//   the same miss-cap. Tile (w:32,h:12,d:16,c:1), exact, maskless.
constexpr int TW = 32, TH = 12, TD = 16;
constexpr int NWT = W_ / TW;             // 5
constexpr int NHT = H_ / TH;             // 16
constexpr int NDT = D_ / TD;             // 4
constexpr int QPP = NWT * NHT;           // 80 blocks per phase
constexpr int CPX = C_ / 8;              // 4 channels per XCD
constexpr int NPH = CPX * NDT;           // 16 phases per XCD
constexpr int LDS_BYTES = 53248;         // 52 KB -> exactly 3 blocks/CU (residency throttle)
constexpr int LSTR = 20;                 // LDS row stride (floats): 16B-aligned f4 reads

typedef float f4_t __attribute__((ext_vector_type(4)));
typedef float f2_t __attribute__((ext_vector_type(2)));

__global__ void __launch_bounds__(256)
affine_grid_sample_kernel(const float* __restrict__ inp,
                          const float* __restrict__ th,
                          float* __restrict__ out)
{
    extern __shared__ float smem[];      // [2][TW][LSTR] used; rest = residency throttle

    const int t   = threadIdx.x;
    const int bid = blockIdx.x;
    const int xcd = bid & 7;             // XCD id (dispatch round-robin assumption)
    int r = bid >> 3;                    // 0..1279 within XCD, in dispatch order
    const int phase = r / QPP;           // 0..15, slowest: one (c,dt) slab at a time
    const int q     = r - phase * QPP;
    const int c  = xcd * CPX + (phase >> 2);
    const int dt = phase & 3;            // dt fastest -> consecutive phases share z-halo
    const int hs = q / NWT;
    const int wt = q - hs * NWT;
    const int w0 = wt * TW, h0 = hs * TH, d0 = dt * TD;

    const float th0=th[0], th1=th[1], th2 =th[2],  th3 =th[3];
    const float th4=th[4], th5=th[5], th6 =th[6],  th7 =th[7];
    const float th8=th[8], th9=th[9], th10=th[10], th11=th[11];

    const float* __restrict__ pc = inp + (size_t)c * DHWi;

    const int w = w0 + (t & 31);
    const int g = t >> 5;                // 0..7: this thread owns d = d0+2g, d0+2g+1
    const float xx = fmaf((float)w, 2.0f / (W_ - 1), -1.0f);

    // per-thread z-constants for its two d's
    float kzx[2], kzy[2], kzz[2];
    #pragma unroll
    for (int kk = 0; kk < 2; ++kk) {
        const int d = d0 + 2 * g + kk;
        const float zz = fmaf((float)d, 2.0f / (D_ - 1), -1.0f);
        kzx[kk] = fmaf(th2,  zz, th3);
        kzy[kk] = fmaf(th6,  zz, th7);
        kzz[kk] = fmaf(th10, zz, th11);
    }

    #pragma unroll 1
    for (int hl = 0; hl < TH; ++hl) {
        const int h = h0 + hl;
        const float yy = fmaf((float)h, 2.0f / (H_ - 1), -1.0f);
        float* __restrict__ L = smem + (hl & 1) * (TW * LSTR);

        // ---- compute both points' offsets, issue all 16 loads, then combine ----
        unsigned o[2][8];
        float u0a[2], u1a[2], v0a[2], v1a[2], s0a[2], s1a[2];
        #pragma unroll
        for (int kk = 0; kk < 2; ++kk) {
            const float px = (fmaf(th0, xx, fmaf(th1, yy, kzx[kk])) + 1.0f) * (0.5f * (W_ - 1));
            const float py = (fmaf(th4, xx, fmaf(th5, yy, kzy[kk])) + 1.0f) * (0.5f * (H_ - 1));
            const float pz = (fmaf(th8, xx, fmaf(th9, yy, kzz[kk])) + 1.0f) * (0.5f * (D_ - 1));
            const float fx = floorf(px), fy = floorf(py), fz = floorf(pz);
            const int ix0 = (int)fx, iy0 = (int)fy, iz0 = (int)fz;
            const int ix1 = ix0 + 1, iy1 = iy0 + 1, iz1 = iz0 + 1;
            const float wx = px - fx, wy = py - fy, wz = pz - fz;
            // zeros-padding: per-axis weight of any OOB corner is zeroed
            u0a[kk] = (ix0 >= 0 && ix0 < W_) ? (1.0f - wx) : 0.0f;
            u1a[kk] = (ix1 >= 0 && ix1 < W_) ? wx          : 0.0f;
            v0a[kk] = (iy0 >= 0 && iy0 < H_) ? (1.0f - wy) : 0.0f;
            v1a[kk] = (iy1 >= 0 && iy1 < H_) ? wy          : 0.0f;
            s0a[kk] = (iz0 >= 0 && iz0 < D_) ? (1.0f - wz) : 0.0f;
            s1a[kk] = (iz1 >= 0 && iz1 < D_) ? wz          : 0.0f;
            const int cx0 = min(max(ix0, 0), W_ - 1), cx1 = min(max(ix1, 0), W_ - 1);
            const int cy0 = min(max(iy0, 0), H_ - 1), cy1 = min(max(iy1, 0), H_ - 1);
            const int cz0 = min(max(iz0, 0), D_ - 1), cz1 = min(max(iz1, 0), D_ - 1);
            const unsigned o00 = (unsigned)(cz0 * HW_ + cy0 * W_);
            const unsigned o01 = (unsigned)(cz0 * HW_ + cy1 * W_);
            const unsigned o10 = (unsigned)(cz1 * HW_ + cy0 * W_);
            const unsigned o11 = (unsigned)(cz1 * HW_ + cy1 * W_);
            o[kk][0] = o00 + (unsigned)cx0;
            o[kk][1] = o00 + (unsigned)cx1;
            o[kk][2] = o01 + (unsigned)cx0;
            o[kk][3] = o01 + (unsigned)cx1;
            o[kk][4] = o10 + (unsigned)cx0;
            o[kk][5] = o10 + (unsigned)cx1;
            o[kk][6] = o11 + (unsigned)cx0;
            o[kk][7] = o11 + (unsigned)cx1;
        }

        float b[2][8];
        #pragma unroll
        for (int kk = 0; kk < 2; ++kk)
            #pragma unroll
            for (int j = 0; j < 8; ++j)
                b[kk][j] = pc[o[kk][j]];

        f2_t val;
        #pragma unroll
        for (int kk = 0; kk < 2; ++kk) {
            const float r00 = u0a[kk] * b[kk][0] + u1a[kk] * b[kk][1];
            const float r01 = u0a[kk] * b[kk][2] + u1a[kk] * b[kk][3];
            const float r10 = u0a[kk] * b[kk][4] + u1a[kk] * b[kk][5];
            const float r11 = u0a[kk] * b[kk][6] + u1a[kk] * b[kk][7];
            const float e0 = v0a[kk] * r00 + v1a[kk] * r01;
            const float e1 = v0a[kk] * r10 + v1a[kk] * r11;
            val[kk] = s0a[kk] * e0 + s1a[kk] * e1;
        }
        // transpose via LDS: row w, k = d-offset (2g, 2g+1); one b64 write
        *(f2_t*)&L[(t & 31) * LSTR + 2 * g] = val;

        __syncthreads();

        // ---- store: 128 threads, full-line float4 NT stores along d ----
        // Double buffer -> no trailing barrier: h+1 writes the other buffer; the
        // h+2 rewrite of this one is ordered behind barrier(h+1), which threads
        // reach only after their LDS reads here retired.
        if (t < 128) {
            const int w2 = t >> 2;       // 0..31
            const int qd = t & 3;        // d-quad
            const f4_t v = *(const f4_t*)&L[w2 * LSTR + 4 * qd];
            float* ob = out + ((size_t)(w0 + w2) * H_ + h) * CD
                            + (size_t)c * D_ + d0 + 4 * qd;
            // output is write-once streaming: non-temporal
            __builtin_nontemporal_store(v, (f4_t*)ob);
        }
    }
}

extern "C" void kernel_launch(void* const* d_in, const int* in_sizes, int n_in,
                              void* d_out, int out_size, void* d_ws, size_t ws_size,
                              hipStream_t stream)
{
    const float* inp = (const float*)d_in[0];   // [1,32,64,192,160] fp32
    const float* th  = (const float*)d_in[1];   // 12 fp32
    float* out = (float*)d_out;                 // [1,160,192,32,64] fp32

    hipLaunchKernelGGL(affine_grid_sample_kernel, dim3(8 * NPH * QPP), dim3(256),
                       LDS_BYTES, stream, inp, th, out);
}